// Round 18
// baseline (638.780 us; speedup 1.0000x reference)
//
#include <hip/hip_runtime.h>
#include <math.h>

#define DIM 7168
#define NE 256
#define NG 8
#define GSZ 32
#define TOPG 4
#define TOPK_N 8
#define NKT 224          // DIM/32 k-tiles total
#define KSPLIT 8
#define KTS 28           // NKT/KSPLIT
#define KSLICE 896       // DIM/KSPLIT
#define BM 64

typedef short bf16x8 __attribute__((ext_vector_type(8)));
typedef float f32x4 __attribute__((ext_vector_type(4)));

#define DREL 4e-5
#define EABS 1e-7
#define FCAP 4096

__device__ __forceinline__ unsigned short bf16_rne(float f) {
    unsigned u = __float_as_uint(f);
    unsigned r = u + 0x7FFFu + ((u >> 16) & 1u);
    return (unsigned short)(r >> 16);
}
__device__ __forceinline__ float bf16_to_f32(unsigned short h) {
    return __uint_as_float(((unsigned)h) << 16);
}

// ---------------- K0: repack W into fragment-major bf16 hi/lo ----------------
__global__ void k0_repack(const float* __restrict__ w,
                          unsigned short* __restrict__ wh,
                          unsigned short* __restrict__ wl) {
    const int gid = blockIdx.x * 256 + threadIdx.x;
    if (gid >= 16 * NKT * 64) return;
    const int l  = gid & 63;
    const int kt = (gid >> 6) % NKT;
    const int ct = gid / (NKT * 64);
    const int e  = ct * 16 + (l & 15);
    const int k0 = kt * 32 + (l >> 4) * 8;
    const float* src = w + (size_t)e * DIM + k0;
    float4 u0 = *(const float4*)src;
    float4 u1 = *(const float4*)(src + 4);
    const float uu[8] = {u0.x, u0.y, u0.z, u0.w, u1.x, u1.y, u1.z, u1.w};
    ushort4 ho[2], lo[2];
    unsigned short* hp = (unsigned short*)ho;
    unsigned short* lp = (unsigned short*)lo;
#pragma unroll
    for (int q = 0; q < 8; ++q) {
        unsigned short hb = bf16_rne(uu[q]);
        float hf = bf16_to_f32(hb);
        unsigned short lb = bf16_rne(uu[q] - hf);
        hp[q] = hb; lp[q] = lb;
    }
    *(ushort4*)(wh + (size_t)gid * 8)     = ho[0];
    *(ushort4*)(wh + (size_t)gid * 8 + 4) = ho[1];
    *(ushort4*)(wl + (size_t)gid * 8)     = lo[0];
    *(ushort4*)(wl + (size_t)gid * 8 + 4) = lo[1];
}

// ---------------- K1: fragment-direct 3-term split-bf16 GEMM, BM=64 ----------------
// grid = (np/64)*8; ks = blockIdx&7 (XCD-pinned B slice); 512 thr, 8 waves.
// wave = (rg, cg): rows (rg*2+rr)*16, ct = cg*4+ci. acc[2][4] = 32 VGPR.
__global__ __launch_bounds__(512, 2) void k1_gemm(
    const float* __restrict__ x,
    const unsigned short* __restrict__ wh, const unsigned short* __restrict__ wl,
    float* __restrict__ part, int n, int np)
{
    const int t  = threadIdx.x;
    const int l  = t & 63;
    const int wv = t >> 6;
    const int ks = blockIdx.x & 7;
    const int rb = blockIdx.x >> 3;
    const int rg = wv >> 2;           // 0..1
    const int cg = wv & 3;            // 0..3
    const int mrow  = l & 15;
    const int kslot = l >> 4;

    f32x4 acc[2][4];
#pragma unroll
    for (int rr = 0; rr < 2; ++rr)
#pragma unroll
        for (int ci = 0; ci < 4; ++ci) acc[rr][ci] = (f32x4){0.f, 0.f, 0.f, 0.f};

    size_t xoff[2];
#pragma unroll
    for (int rr = 0; rr < 2; ++rr) {
        int row = rb * BM + (rg * 2 + rr) * 16 + mrow;
        if (row > n - 1) row = n - 1;
        xoff[rr] = (size_t)row * DIM + (size_t)ks * KSLICE + kslot * 8;
    }
    const size_t bbase = (size_t)l * 8;

#pragma unroll 1
    for (int tt = 0; tt < KTS; ++tt) {
        bf16x8 ah[2], al[2];
#pragma unroll
        for (int rr = 0; rr < 2; ++rr) {
            const float* xp = x + xoff[rr] + (size_t)tt * 32;
            float4 u0 = *(const float4*)xp;
            float4 u1 = *(const float4*)(xp + 4);
            const float uu[8] = {u0.x, u0.y, u0.z, u0.w, u1.x, u1.y, u1.z, u1.w};
            bf16x8 hh, ll;
#pragma unroll
            for (int q = 0; q < 8; ++q) {
                const unsigned u  = __float_as_uint(uu[q]);
                const unsigned hr = (u + 0x7FFFu + ((u >> 16) & 1u)) & 0xFFFF0000u;
                const float lofv  = uu[q] - __uint_as_float(hr);
                hh[q] = (short)(hr >> 16);
                ll[q] = (short)(__float_as_uint(lofv) >> 16);
            }
            ah[rr] = hh; al[rr] = ll;
        }
#pragma unroll
        for (int ci = 0; ci < 4; ++ci) {
            const int ct = cg * 4 + ci;
            const size_t fb = ((size_t)(ct * NKT + ks * KTS + tt) * 64) * 8 + bbase;
            const bf16x8 bh = *(const bf16x8*)(wh + fb);
            const bf16x8 bl = *(const bf16x8*)(wl + fb);
#pragma unroll
            for (int rr = 0; rr < 2; ++rr) {
                acc[rr][ci] = __builtin_amdgcn_mfma_f32_16x16x32_bf16(ah[rr], bh, acc[rr][ci], 0, 0, 0);
                acc[rr][ci] = __builtin_amdgcn_mfma_f32_16x16x32_bf16(ah[rr], bl, acc[rr][ci], 0, 0, 0);
                acc[rr][ci] = __builtin_amdgcn_mfma_f32_16x16x32_bf16(al[rr], bh, acc[rr][ci], 0, 0, 0);
            }
        }
    }

    // D layout: col = lane&15 (expert), row = 4*(lane>>4)+j (verified r7/r8)
    float* pb = part + (size_t)ks * np * NE;
#pragma unroll
    for (int rr = 0; rr < 2; ++rr)
#pragma unroll
        for (int ci = 0; ci < 4; ++ci) {
            const int rl = rb * BM + (rg * 2 + rr) * 16 + 4 * kslot;
            const int e  = (cg * 4 + ci) * 16 + mrow;
#pragma unroll
            for (int j = 0; j < 4; ++j)
                pb[(size_t)(rl + j) * NE + e] = acc[rr][ci][j];
        }
}

// ---------------- K1b-sum: TLP streaming combine -> zbuf ----------------
#define RSB 4
__global__ __launch_bounds__(256) void k1b_sum(
    const float* __restrict__ part, float* __restrict__ zbuf, int np)
{
    const int t  = threadIdx.x;
    const int r0 = blockIdx.x * RSB;
#pragma unroll
    for (int r = 0; r < RSB; ++r) {
        const size_t off = (size_t)(r0 + r) * NE + t;
        float z = 0.f;
#pragma unroll
        for (int ks = 0; ks < KSPLIT; ++ks)
            z += part[(size_t)ks * np * NE + off];
        zbuf[off] = z;
    }
}

// ---------------- K1b-tail v4: precompute-s + destructive f32 argmax ----------------
#define SCW 260
__global__ __launch_bounds__(256) void k1b_tail(
    const float* __restrict__ zbuf, const float* __restrict__ bias,
    float* __restrict__ out, unsigned* __restrict__ counter,
    int* __restrict__ list, int n, unsigned lcap)
{
    __shared__ __align__(16) float sc[32][SCW];
    __shared__ float sbias[NE];
    const int t  = threadIdx.x;
    const int r0 = blockIdx.x * 32;
    sbias[t] = bias[t];
#pragma unroll
    for (int r = 0; r < 32; ++r)
        sc[r][t] = zbuf[(size_t)(r0 + r) * NE + t];
    __syncthreads();

    if (t < 32) {
        const int row = r0 + t;
        if (row < n) {
            float* srow = sc[t];
            float zmaxf = -3e38f;
            for (int e = 0; e < NE; ++e) zmaxf = fmaxf(zmaxf, srow[e]);
            double Z = 0.0;
            for (int e = 0; e < NE; ++e) {
                float p = __expf(srow[e] - zmaxf);
                srow[e] = p;
                Z += (double)p;
            }
            const double invZ = 1.0 / Z;

            bool flag = false;
            double gs[NG], dg[NG];
#pragma unroll
            for (int g = 0; g < NG; ++g) {
                double v1 = -1e300, v2 = -1e300, v3 = -1e300;
                double d1 = 0, d2 = 0, d3 = 0;
                for (int i = 0; i < GSZ; ++i) {
                    const int e = g * GSZ + i;
                    double p = (double)srow[e] * invZ;
                    double v = p + (double)sbias[e];
                    double d = DREL * p;
                    srow[e] = (float)v;
                    if (v > v1)      { v3 = v2; d3 = d2; v2 = v1; d2 = d1; v1 = v; d1 = d; }
                    else if (v > v2) { v3 = v2; d3 = d2; v2 = v;  d2 = d; }
                    else if (v > v3) { v3 = v;  d3 = d; }
                }
                if (v2 - v3 <= d2 + d3) flag = true;
                gs[g] = v1 + v2; dg[g] = d1 + d2;
            }
            unsigned keep = 0;
#pragma unroll
            for (int tt = 0; tt < TOPG; ++tt) {
                double best = -1e300; int bg = 0;
#pragma unroll
                for (int g = 0; g < NG; ++g)
                    if (!((keep >> g) & 1u) && gs[g] > best) { best = gs[g]; bg = g; }
                keep |= 1u << bg;
            }
            {
                double mn = 1e300, mx = -1e300;
#pragma unroll
                for (int g = 0; g < NG; ++g) {
                    if ((keep >> g) & 1u) mn = fmin(mn, gs[g] - dg[g]);
                    else                  mx = fmax(mx, gs[g] + dg[g]);
                }
                if (mn <= mx) flag = true;
            }
#pragma unroll
            for (int g = 0; g < NG; ++g) {
                if (!((keep >> g) & 1u)) {
#pragma unroll
                    for (int i = 0; i < GSZ; i += 4)
                        *(float4*)&srow[g * GSZ + i] =
                            make_float4(-3e38f, -3e38f, -3e38f, -3e38f);
                }
            }
            double pbest = 0.0, pbd = 0.0;
            float* out_w = out;
            float* out_i = out + (size_t)n * TOPK_N;
            for (int pp = 0; pp < 9; ++pp) {
                float best = -3e38f; int be = 0;
                for (int i = 0; i < NE / 4; ++i) {
                    const float4 v = *(const float4*)&srow[4 * i];
                    float m01 = (v.x >= v.y) ? v.x : v.y;
                    int   i01 = (v.x >= v.y) ? 0 : 1;
                    float m23 = (v.z >= v.w) ? v.z : v.w;
                    int   i23 = (v.z >= v.w) ? 2 : 3;
                    float m   = (m01 >= m23) ? m01 : m23;
                    int   iq  = (m01 >= m23) ? i01 : i23;
                    if (m > best) { best = m; be = 4 * i + iq; }
                }
                const double pt = fmax((double)best - (double)sbias[be], 0.0);
                const double bd = DREL * pt + EABS;
                if (pp < TOPK_N) {
                    out_w[(size_t)row * TOPK_N + pp] = (float)(pt * 2.5);
                    out_i[(size_t)row * TOPK_N + pp] = (float)be;
                }
                if (pp > 0 && pbest - (double)best <= pbd + bd) flag = true;
                pbest = (double)best; pbd = bd;
                srow[be] = -3e38f;
            }
            if (flag) {
                unsigned idx = atomicAdd(counter, 1u);
                if (idx < lcap) list[idx] = row;
            }
        }
    }
}

// ---------------- K2 v5: fp64 partials, 16 rows x k-slice per block (r13, proven) ----------------
#define K2R 16
#define K2C 32
__global__ __launch_bounds__(256) void k2_exact(
    const float* __restrict__ x, const float* __restrict__ w,
    double* __restrict__ part2,
    const unsigned* __restrict__ counter, const int* __restrict__ list,
    unsigned lcap)
{
    __shared__ float wlds[NE][K2C + 1];
    __shared__ float xc[K2R][K2C];

    const unsigned F = min(*counter, lcap);
    const int ks = blockIdx.x & 7;
    const int rc = blockIdx.x >> 3;
    if ((unsigned)(rc * K2R) >= F) return;
    const int t = threadIdx.x;

    int rows[K2R];
#pragma unroll
    for (int i = 0; i < K2R; ++i) {
        unsigned idx = (unsigned)(rc * K2R + i);
        if (idx >= F) idx = 0;
        rows[i] = list[idx];
    }

    const int se = t >> 3;
    const int sp = (t & 7) * 4;
    const int xrr = t >> 3;
    const size_t kbase = (size_t)ks * KSLICE;

    double acc[K2R];
#pragma unroll
    for (int i = 0; i < K2R; ++i) acc[i] = 0.0;

    float4 wr[8];
#pragma unroll
    for (int it = 0; it < 8; ++it)
        wr[it] = *(const float4*)&w[(size_t)(it * 32 + se) * DIM + kbase + sp];
    float4 xr = make_float4(0.f, 0.f, 0.f, 0.f);
    if (t < 128) xr = *(const float4*)&x[(size_t)rows[xrr] * DIM + kbase + sp];

    for (int c = 0; c < KSLICE / K2C; ++c) {
        __syncthreads();
#pragma unroll
        for (int it = 0; it < 8; ++it) {
            const float* wp = (const float*)&wr[it];
#pragma unroll
            for (int q = 0; q < 4; ++q)
                wlds[it * 32 + se][sp + q] = wp[q];
        }
        if (t < 128)
            *(float4*)&xc[xrr][sp] = xr;
        {
            const int cn = (c + 1 < KSLICE / K2C) ? c + 1 : c;
            const size_t k0 = kbase + (size_t)cn * K2C;
#pragma unroll
            for (int it = 0; it < 8; ++it)
                wr[it] = *(const float4*)&w[(size_t)(it * 32 + se) * DIM + k0 + sp];
            if (t < 128) xr = *(const float4*)&x[(size_t)rows[xrr] * DIM + k0 + sp];
        }
        __syncthreads();
#pragma unroll
        for (int i = 0; i < 8; ++i) {
            float wv[4];
#pragma unroll
            for (int q = 0; q < 4; ++q) wv[q] = wlds[t][i * 4 + q];
#pragma unroll
            for (int r = 0; r < K2R; ++r) {
                const float4 xv = *(const float4*)&xc[r][i * 4];
                const float* xp = (const float*)&xv;
#pragma unroll
                for (int q = 0; q < 4; ++q)
                    acc[r] = fma((double)xp[q], (double)wv[q], acc[r]);
            }
        }
    }

#pragma unroll
    for (int r = 0; r < K2R; ++r) {
        const unsigned idx = (unsigned)(rc * K2R + r);
        if (idx < F)
            part2[((size_t)idx * 8 + ks) * NE + t] = acc[r];
    }
}

// ---------------- K2b: combine 8 fp64 slices + exact routing (register-tk) ----------------
__global__ __launch_bounds__(256) void k2b_route(
    const double* __restrict__ part2, const float* __restrict__ bias,
    float* __restrict__ out, const unsigned* __restrict__ counter,
    const int* __restrict__ list, int n, unsigned lcap)
{
    __shared__ double sc[NE];
    const unsigned F = min(*counter, lcap);
    const unsigned b = blockIdx.x;
    if (b >= F) return;
    const int t = threadIdx.x;

    double s = 0.0;
#pragma unroll
    for (int ks = 0; ks < 8; ++ks)
        s += part2[((size_t)b * 8 + ks) * NE + t];
    sc[t] = s;
    __syncthreads();

    if (t == 0) {
        const int row = list[b];
        double* srow = sc;
        double zmax = -1e300;
        for (int ee = 0; ee < NE; ++ee) zmax = fmax(zmax, srow[ee]);
        double Z = 0.0;
        for (int ee = 0; ee < NE; ++ee) {
            double p = exp(srow[ee] - zmax);
            srow[ee] = p;
            Z += p;
        }
        const double invZ = 1.0 / Z;
        double gs[NG];
#pragma unroll
        for (int g = 0; g < NG; ++g) {
            double m1 = -1e300, m2 = -1e300;
            for (int i = 0; i < GSZ; ++i) {
                double v = srow[g * GSZ + i] * invZ + (double)bias[g * GSZ + i];
                if (v > m1) { m2 = m1; m1 = v; }
                else if (v > m2) { m2 = v; }
            }
            gs[g] = m1 + m2;
        }
        unsigned keep = 0;
#pragma unroll
        for (int tt = 0; tt < TOPG; ++tt) {
            double best = -1e300; int bg = 0;
#pragma unroll
            for (int g = 0; g < NG; ++g)
                if (!((keep >> g) & 1u) && gs[g] > best) { best = gs[g]; bg = g; }
            keep |= 1u << bg;
        }
        unsigned long long tk0 = 0ull, tk1 = 0ull, tk2 = 0ull, tk3 = 0ull;
        float* out_w = out;
        float* out_i = out + (size_t)n * TOPK_N;
        for (int pp = 0; pp < TOPK_N; ++pp) {
            double best = -1e300; int be = 0;
            for (int ee = 0; ee < NE; ++ee) {
                const bool gok = (keep >> (ee >> 5)) & 1u;
                const unsigned long long m =
                    (ee < 128) ? ((ee < 64) ? tk0 : tk1) : ((ee < 192) ? tk2 : tk3);
                const bool tok = !((m >> (ee & 63)) & 1ull);
                const double ss = srow[ee] * invZ + (double)bias[ee];
                if (gok && tok && ss > best) { best = ss; be = ee; }
            }
            const unsigned long long bit = 1ull << (be & 63);
            if (be < 64)       tk0 |= bit;
            else if (be < 128) tk1 |= bit;
            else if (be < 192) tk2 |= bit;
            else               tk3 |= bit;
            out_w[(size_t)row * TOPK_N + pp] = (float)(srow[be] * invZ * 2.5);
            out_i[(size_t)row * TOPK_N + pp] = (float)be;
        }
    }
}

// ---------------- fallback (proven r6 fp64 kernel) if ws too small ----------------
#define OBM 32
#define OBK 16
#define ONCH (DIM / OBK)
__global__ __launch_bounds__(512) void gate_kernel_old(
    const float* __restrict__ x, const float* __restrict__ w,
    const float* __restrict__ bias, float* __restrict__ out, int n)
{
    __shared__ __align__(16) char smem[65536];
    float  (*w2)[OBK][NE] = reinterpret_cast<float(*)[OBK][NE]>(smem);
    double (*x2)[OBK][34] = reinterpret_cast<double(*)[OBK][34]>(smem + 32768);
    double (*sc)[OBM]     = reinterpret_cast<double(*)[OBM]>(smem);
    const int t = threadIdx.x;
    const int row0 = blockIdx.x * OBM;
    const int we = t & 255;
    const int h8 = (t >> 8) * 8;
    const size_t wbase = (size_t)we * DIM + h8;
    const int rx = t >> 2;
    const int kx = (t & 3) * 4;
    int rr = row0 + rx; if (rr > n - 1) rr = n - 1;
    const size_t xbase = (size_t)rr * DIM + kx;
    const int wv = t >> 6, lane = t & 63;
    const int h = wv & 1, rg = wv >> 1, rb = 8 * rg;
    const int e0 = 128 * h + 2 * lane;
    double acc[8][2];
#pragma unroll
    for (int i = 0; i < 8; ++i) { acc[i][0] = 0.0; acc[i][1] = 0.0; }
    float4 wra = *(const float4*)&w[wbase];
    float4 wrb = *(const float4*)&w[wbase + 4];
    float4 xr = make_float4(0.f, 0.f, 0.f, 0.f);
    if (t < 128) xr = *(const float4*)&x[xbase];
    for (int c = 0; c < ONCH; ++c) {
        const int b = c & 1;
        const float* fa = (const float*)&wra;
        const float* fb = (const float*)&wrb;
#pragma unroll
        for (int q = 0; q < 4; ++q) {
            w2[b][h8 + q][we] = fa[q];
            w2[b][h8 + 4 + q][we] = fb[q];
        }
        if (t < 128) {
            const float* fx = (const float*)&xr;
#pragma unroll
            for (int q = 0; q < 4; ++q) x2[b][kx + q][rx] = (double)fx[q];
        }
        const size_t k0 = (size_t)((c + 1 < ONCH) ? c + 1 : c) * OBK;
        wra = *(const float4*)&w[wbase + k0];
        wrb = *(const float4*)&w[wbase + k0 + 4];
        if (t < 128) xr = *(const float4*)&x[xbase + k0];
        __syncthreads();
#pragma unroll
        for (int kk = 0; kk < OBK; ++kk) {
            const float2 wf = *(const float2*)&w2[b][kk][e0];
            const double wd0 = (double)wf.x, wd1 = (double)wf.y;
            const double2 xp0 = *(const double2*)&x2[b][kk][rb];
            const double2 xp1 = *(const double2*)&x2[b][kk][rb + 2];
            const double2 xp2 = *(const double2*)&x2[b][kk][rb + 4];
            const double2 xp3 = *(const double2*)&x2[b][kk][rb + 6];
            const double xv[8] = {xp0.x, xp0.y, xp1.x, xp1.y, xp2.x, xp2.y, xp3.x, xp3.y};
#pragma unroll
            for (int i = 0; i < 8; ++i) {
                acc[i][0] = fma(xv[i], wd0, acc[i][0]);
                acc[i][1] = fma(xv[i], wd1, acc[i][1]);
            }
        }
    }
    __syncthreads();
#pragma unroll
    for (int j = 0; j < 2; ++j)
#pragma unroll
        for (int q = 0; q < 4; ++q) {
            double2 v; v.x = acc[2 * q][j]; v.y = acc[2 * q + 1][j];
            *(double2*)&sc[e0 + j][rb + 2 * q] = v;
        }
    __syncthreads();
    if (t < OBM) {
        const int row = row0 + t;
        if (row < n) {
            double zmax = -1e300;
            for (int e = 0; e < NE; ++e) zmax = fmax(zmax, sc[e][t]);
            double Z = 0.0;
            for (int e = 0; e < NE; ++e) { double p = exp(sc[e][t] - zmax); sc[e][t] = p; Z += p; }
            const double invZ = 1.0 / Z;
            double gs[NG];
            for (int g = 0; g < NG; ++g) {
                double m1 = -1e300, m2 = -1e300;
                for (int i = 0; i < GSZ; ++i) {
                    double v = sc[g * GSZ + i][t] * invZ + (double)bias[g * GSZ + i];
                    if (v > m1) { m2 = m1; m1 = v; } else if (v > m2) m2 = v;
                }
                gs[g] = m1 + m2;
            }
            unsigned keep = 0;
            for (int tt = 0; tt < TOPG; ++tt) {
                double best = -1e300; int bg = 0;
                for (int g = 0; g < NG; ++g)
                    if (!((keep >> g) & 1u) && gs[g] > best) { best = gs[g]; bg = g; }
                keep |= 1u << bg;
            }
            unsigned long long tk[4] = {0ull, 0ull, 0ull, 0ull};
            float* out_w = out;
            float* out_i = out + (size_t)n * TOPK_N;
            for (int pp = 0; pp < TOPK_N; ++pp) {
                double best = -1e300; int be = 0;
                for (int e = 0; e < NE; ++e) {
                    if (!((keep >> (e >> 5)) & 1u)) continue;
                    if ((tk[e >> 6] >> (e & 63)) & 1ull) continue;
                    double s = sc[e][t] * invZ + (double)bias[e];
                    if (s > best) { best = s; be = e; }
                }
                tk[be >> 6] |= 1ull << (be & 63);
                out_w[(size_t)row * TOPK_N + pp] = (float)(sc[be][t] * invZ * 2.5);
                out_i[(size_t)row * TOPK_N + pp] = (float)be;
            }
        }
    }
}

extern "C" void kernel_launch(void* const* d_in, const int* in_sizes, int n_in,
                              void* d_out, int out_size, void* d_ws, size_t ws_size,
                              hipStream_t stream) {
    const float* x  = (const float*)d_in[0];
    const float* w  = (const float*)d_in[1];
    const float* b  = (const float*)d_in[2];
    float* out      = (float*)d_out;
    const int n     = in_sizes[0] / DIM;
    const int np    = (n + 63) & ~63;          // BM=64 alignment
    const int nrb   = np / BM;

    const size_t WBYTES   = (size_t)16 * NKT * 64 * 8 * 2;
    const size_t off_list = 4096;
    const size_t off_wh   = off_list + (((size_t)np * 4 + 255) & ~(size_t)255);
    const size_t off_wl   = off_wh + WBYTES;
    const size_t off_part = off_wl + WBYTES;
    const size_t part_sz  = (size_t)KSPLIT * np * NE * 4;
    const size_t p2_sz    = (size_t)FCAP * 8 * NE * 8;
    const size_t off_z    = off_part + (part_sz > p2_sz ? part_sz : p2_sz);
    const size_t z_sz     = (size_t)np * NE * 4;
    const size_t need     = off_z + z_sz;

    if (ws_size < need || (np & 31)) {
        gate_kernel_old<<<(n + OBM - 1) / OBM, 512, 0, stream>>>(x, w, b, out, n);
        return;
    }
    char* ws = (char*)d_ws;
    unsigned* flagctr   = (unsigned*)ws;
    int* list           = (int*)(ws + off_list);
    unsigned short* wh  = (unsigned short*)(ws + off_wh);
    unsigned short* wl  = (unsigned short*)(ws + off_wl);
    float* part         = (float*)(ws + off_part);
    double* part2       = (double*)(ws + off_part);
    float* zbuf         = (float*)(ws + off_z);

    const unsigned lcap = (unsigned)((np < FCAP) ? np : FCAP);

    hipMemsetAsync(ws, 0, 64, stream);
    k0_repack<<<(16 * NKT * 64) / 256, 256, 0, stream>>>(w, wh, wl);
    k1_gemm<<<nrb * KSPLIT, 512, 0, stream>>>(x, wh, wl, part, n, np);
    k1b_sum<<<np / RSB, 256, 0, stream>>>(part, zbuf, np);
    k1b_tail<<<np / 32, 256, 0, stream>>>(zbuf, b, out, flagctr, list, n, lcap);
    k2_exact<<<((lcap + K2R - 1) / K2R) * 8, 256, 0, stream>>>(x, w, part2, flagctr, list, lcap);
    k2b_route<<<lcap, 256, 0, stream>>>(part2, b, out, flagctr, list, n, lcap);
}

// Round 19
// 606.133 us; speedup vs baseline: 1.0539x; 1.0539x over previous
//
#include <hip/hip_runtime.h>
#include <math.h>

#define DIM 7168
#define NE 256
#define NG 8
#define GSZ 32
#define TOPG 4
#define TOPK_N 8
#define NKT 224          // DIM/32 k-tiles total
#define KSPLIT 8
#define KTS 28           // NKT/KSPLIT
#define KSLICE 896       // DIM/KSPLIT
#define BM 128

typedef short bf16x8 __attribute__((ext_vector_type(8)));
typedef float f32x4 __attribute__((ext_vector_type(4)));

#define DREL 4e-5
#define EABS 1e-7
#define FCAP 4096

__device__ __forceinline__ unsigned short bf16_rne(float f) {
    unsigned u = __float_as_uint(f);
    unsigned r = u + 0x7FFFu + ((u >> 16) & 1u);
    return (unsigned short)(r >> 16);
}
__device__ __forceinline__ float bf16_to_f32(unsigned short h) {
    return __uint_as_float(((unsigned)h) << 16);
}

// ---------------- K0: repack W into fragment-major bf16 hi/lo ----------------
__global__ void k0_repack(const float* __restrict__ w,
                          unsigned short* __restrict__ wh,
                          unsigned short* __restrict__ wl) {
    const int gid = blockIdx.x * 256 + threadIdx.x;
    if (gid >= 16 * NKT * 64) return;
    const int l  = gid & 63;
    const int kt = (gid >> 6) % NKT;
    const int ct = gid / (NKT * 64);
    const int e  = ct * 16 + (l & 15);
    const int k0 = kt * 32 + (l >> 4) * 8;
    const float* src = w + (size_t)e * DIM + k0;
    float4 u0 = *(const float4*)src;
    float4 u1 = *(const float4*)(src + 4);
    const float uu[8] = {u0.x, u0.y, u0.z, u0.w, u1.x, u1.y, u1.z, u1.w};
    ushort4 ho[2], lo[2];
    unsigned short* hp = (unsigned short*)ho;
    unsigned short* lp = (unsigned short*)lo;
#pragma unroll
    for (int q = 0; q < 8; ++q) {
        unsigned short hb = bf16_rne(uu[q]);
        float hf = bf16_to_f32(hb);
        unsigned short lb = bf16_rne(uu[q] - hf);
        hp[q] = hb; lp[q] = lb;
    }
    *(ushort4*)(wh + (size_t)gid * 8)     = ho[0];
    *(ushort4*)(wh + (size_t)gid * 8 + 4) = ho[1];
    *(ushort4*)(wl + (size_t)gid * 8)     = lo[0];
    *(ushort4*)(wl + (size_t)gid * 8 + 4) = lo[1];
}

// ---------------- K1: fragment-direct split-bf16 GEMM, BM=128, SW-pipelined ----------------
// grid = (np/128)*8; ks = blockIdx&7 (XCD-pinned B slice); 512 thr, 8 waves.
// B-frags double-buffered by half (8 frag-pairs each); x prefetched 1 tt ahead.
__global__ __launch_bounds__(512, 2) void k1_gemm(
    const float* __restrict__ x,
    const unsigned short* __restrict__ wh, const unsigned short* __restrict__ wl,
    float* __restrict__ part, int n, int np)
{
    const int t  = threadIdx.x;
    const int l  = t & 63;
    const int wv = t >> 6;
    const int ks = blockIdx.x & 7;
    const int rb = blockIdx.x >> 3;
    const int rtb = 2 * (wv & 3);
    const int ctb = 8 * (wv >> 2);
    const int mrow  = l & 15;
    const int kslot = l >> 4;

    f32x4 acc[2][8];
#pragma unroll
    for (int rr = 0; rr < 2; ++rr)
#pragma unroll
        for (int ci = 0; ci < 8; ++ci) acc[rr][ci] = (f32x4){0.f, 0.f, 0.f, 0.f};

    size_t xoff[2];
#pragma unroll
    for (int rr = 0; rr < 2; ++rr) {
        int row = rb * BM + (rtb + rr) * 16 + mrow;
        if (row > n - 1) row = n - 1;
        xoff[rr] = (size_t)row * DIM + (size_t)ks * KSLICE + kslot * 8;
    }
    const size_t bbase = (size_t)l * 8;

    auto loadB = [&](int ttl, int half, bf16x8* dh, bf16x8* dl) {
#pragma unroll
        for (int ci = 0; ci < 4; ++ci) {
            const int ct = ctb + half * 4 + ci;
            const size_t fb = ((size_t)(ct * NKT + ks * KTS + ttl) * 64) * 8 + bbase;
            dh[ci] = *(const bf16x8*)(wh + fb);
            dl[ci] = *(const bf16x8*)(wl + fb);
        }
    };
    auto splitx = [&](float4 u0, float4 u1, bf16x8& hh, bf16x8& ll) {
        const float uu[8] = {u0.x, u0.y, u0.z, u0.w, u1.x, u1.y, u1.z, u1.w};
        bf16x8 h, lo;
#pragma unroll
        for (int q = 0; q < 8; ++q) {
            const unsigned u  = __float_as_uint(uu[q]);
            const unsigned hr = (u + 0x7FFFu + ((u >> 16) & 1u)) & 0xFFFF0000u;
            const float lofv  = uu[q] - __uint_as_float(hr);
            h[q]  = (short)(hr >> 16);
            lo[q] = (short)(__float_as_uint(lofv) >> 16);
        }
        hh = h; ll = lo;
    };

    // pipeline state: buf0 holds half0 frags, buf1 holds half1 frags
    bf16x8 bhb[2][4], blb[2][4];
    float4 px0a, px0b, px1a, px1b;

    // preload x(tt=0) and B(tt=0, half0)
    px0a = *(const float4*)(x + xoff[0]);
    px0b = *(const float4*)(x + xoff[0] + 4);
    px1a = *(const float4*)(x + xoff[1]);
    px1b = *(const float4*)(x + xoff[1] + 4);
    loadB(0, 0, bhb[0], blb[0]);

#pragma unroll 1
    for (int tt = 0; tt < KTS; ++tt) {
        const int tn = (tt + 1 < KTS) ? tt + 1 : tt;
        // split current x
        bf16x8 ah0, al0, ah1, al1;
        splitx(px0a, px0b, ah0, al0);
        splitx(px1a, px1b, ah1, al1);
        // prefetch x(tt+1)
        px0a = *(const float4*)(x + xoff[0] + (size_t)tn * 32);
        px0b = *(const float4*)(x + xoff[0] + (size_t)tn * 32 + 4);
        px1a = *(const float4*)(x + xoff[1] + (size_t)tn * 32);
        px1b = *(const float4*)(x + xoff[1] + (size_t)tn * 32 + 4);
        // phase 0: prefetch half1(tt), MFMA half0 from buf0
        loadB(tt, 1, bhb[1], blb[1]);
#pragma unroll
        for (int ci = 0; ci < 4; ++ci) {
            acc[0][ci] = __builtin_amdgcn_mfma_f32_16x16x32_bf16(ah0, bhb[0][ci], acc[0][ci], 0, 0, 0);
            acc[0][ci] = __builtin_amdgcn_mfma_f32_16x16x32_bf16(ah0, blb[0][ci], acc[0][ci], 0, 0, 0);
            acc[0][ci] = __builtin_amdgcn_mfma_f32_16x16x32_bf16(al0, bhb[0][ci], acc[0][ci], 0, 0, 0);
            acc[1][ci] = __builtin_amdgcn_mfma_f32_16x16x32_bf16(ah1, bhb[0][ci], acc[1][ci], 0, 0, 0);
            acc[1][ci] = __builtin_amdgcn_mfma_f32_16x16x32_bf16(ah1, blb[0][ci], acc[1][ci], 0, 0, 0);
            acc[1][ci] = __builtin_amdgcn_mfma_f32_16x16x32_bf16(al1, bhb[0][ci], acc[1][ci], 0, 0, 0);
        }
        // phase 1: prefetch half0(tt+1), MFMA half1 from buf1
        loadB(tn, 0, bhb[0], blb[0]);
#pragma unroll
        for (int ci = 0; ci < 4; ++ci) {
            acc[0][4 + ci] = __builtin_amdgcn_mfma_f32_16x16x32_bf16(ah0, bhb[1][ci], acc[0][4 + ci], 0, 0, 0);
            acc[0][4 + ci] = __builtin_amdgcn_mfma_f32_16x16x32_bf16(ah0, blb[1][ci], acc[0][4 + ci], 0, 0, 0);
            acc[0][4 + ci] = __builtin_amdgcn_mfma_f32_16x16x32_bf16(al0, bhb[1][ci], acc[0][4 + ci], 0, 0, 0);
            acc[1][4 + ci] = __builtin_amdgcn_mfma_f32_16x16x32_bf16(ah1, bhb[1][ci], acc[1][4 + ci], 0, 0, 0);
            acc[1][4 + ci] = __builtin_amdgcn_mfma_f32_16x16x32_bf16(ah1, blb[1][ci], acc[1][4 + ci], 0, 0, 0);
            acc[1][4 + ci] = __builtin_amdgcn_mfma_f32_16x16x32_bf16(al1, bhb[1][ci], acc[1][4 + ci], 0, 0, 0);
        }
    }

    // D layout: col = lane&15 (expert), row = 4*(lane>>4)+j (verified r7/r8)
    float* pb = part + (size_t)ks * np * NE;
#pragma unroll
    for (int rr = 0; rr < 2; ++rr)
#pragma unroll
        for (int ci = 0; ci < 8; ++ci) {
            const int rl = rb * BM + (rtb + rr) * 16 + 4 * kslot;
            const int e  = (ctb + ci) * 16 + mrow;
#pragma unroll
            for (int j = 0; j < 4; ++j)
                pb[(size_t)(rl + j) * NE + e] = acc[rr][ci][j];
        }
}

// ---------------- K1b-sum: TLP streaming combine -> zbuf ----------------
#define RSB 4
__global__ __launch_bounds__(256) void k1b_sum(
    const float* __restrict__ part, float* __restrict__ zbuf, int np)
{
    const int t  = threadIdx.x;
    const int r0 = blockIdx.x * RSB;
#pragma unroll
    for (int r = 0; r < RSB; ++r) {
        const size_t off = (size_t)(r0 + r) * NE + t;
        float z = 0.f;
#pragma unroll
        for (int ks = 0; ks < KSPLIT; ++ks)
            z += part[(size_t)ks * np * NE + off];
        zbuf[off] = z;
    }
}

// ---------------- K1b-tail v4: precompute-s + destructive f32 argmax ----------------
#define SCW 260
__global__ __launch_bounds__(256) void k1b_tail(
    const float* __restrict__ zbuf, const float* __restrict__ bias,
    float* __restrict__ out, unsigned* __restrict__ counter,
    int* __restrict__ list, int n, unsigned lcap)
{
    __shared__ __align__(16) float sc[32][SCW];
    __shared__ float sbias[NE];
    const int t  = threadIdx.x;
    const int r0 = blockIdx.x * 32;
    sbias[t] = bias[t];
#pragma unroll
    for (int r = 0; r < 32; ++r)
        sc[r][t] = zbuf[(size_t)(r0 + r) * NE + t];
    __syncthreads();

    if (t < 32) {
        const int row = r0 + t;
        if (row < n) {
            float* srow = sc[t];
            float zmaxf = -3e38f;
            for (int e = 0; e < NE; ++e) zmaxf = fmaxf(zmaxf, srow[e]);
            double Z = 0.0;
            for (int e = 0; e < NE; ++e) {
                float p = __expf(srow[e] - zmaxf);
                srow[e] = p;
                Z += (double)p;
            }
            const double invZ = 1.0 / Z;

            bool flag = false;
            double gs[NG], dg[NG];
#pragma unroll
            for (int g = 0; g < NG; ++g) {
                double v1 = -1e300, v2 = -1e300, v3 = -1e300;
                double d1 = 0, d2 = 0, d3 = 0;
                for (int i = 0; i < GSZ; ++i) {
                    const int e = g * GSZ + i;
                    double p = (double)srow[e] * invZ;
                    double v = p + (double)sbias[e];
                    double d = DREL * p;
                    srow[e] = (float)v;
                    if (v > v1)      { v3 = v2; d3 = d2; v2 = v1; d2 = d1; v1 = v; d1 = d; }
                    else if (v > v2) { v3 = v2; d3 = d2; v2 = v;  d2 = d; }
                    else if (v > v3) { v3 = v;  d3 = d; }
                }
                if (v2 - v3 <= d2 + d3) flag = true;
                gs[g] = v1 + v2; dg[g] = d1 + d2;
            }
            unsigned keep = 0;
#pragma unroll
            for (int tt = 0; tt < TOPG; ++tt) {
                double best = -1e300; int bg = 0;
#pragma unroll
                for (int g = 0; g < NG; ++g)
                    if (!((keep >> g) & 1u) && gs[g] > best) { best = gs[g]; bg = g; }
                keep |= 1u << bg;
            }
            {
                double mn = 1e300, mx = -1e300;
#pragma unroll
                for (int g = 0; g < NG; ++g) {
                    if ((keep >> g) & 1u) mn = fmin(mn, gs[g] - dg[g]);
                    else                  mx = fmax(mx, gs[g] + dg[g]);
                }
                if (mn <= mx) flag = true;
            }
#pragma unroll
            for (int g = 0; g < NG; ++g) {
                if (!((keep >> g) & 1u)) {
#pragma unroll
                    for (int i = 0; i < GSZ; i += 4)
                        *(float4*)&srow[g * GSZ + i] =
                            make_float4(-3e38f, -3e38f, -3e38f, -3e38f);
                }
            }
            double pbest = 0.0, pbd = 0.0;
            float* out_w = out;
            float* out_i = out + (size_t)n * TOPK_N;
            for (int pp = 0; pp < 9; ++pp) {
                float best = -3e38f; int be = 0;
                for (int i = 0; i < NE / 4; ++i) {
                    const float4 v = *(const float4*)&srow[4 * i];
                    float m01 = (v.x >= v.y) ? v.x : v.y;
                    int   i01 = (v.x >= v.y) ? 0 : 1;
                    float m23 = (v.z >= v.w) ? v.z : v.w;
                    int   i23 = (v.z >= v.w) ? 2 : 3;
                    float m   = (m01 >= m23) ? m01 : m23;
                    int   iq  = (m01 >= m23) ? i01 : i23;
                    if (m > best) { best = m; be = 4 * i + iq; }
                }
                const double pt = fmax((double)best - (double)sbias[be], 0.0);
                const double bd = DREL * pt + EABS;
                if (pp < TOPK_N) {
                    out_w[(size_t)row * TOPK_N + pp] = (float)(pt * 2.5);
                    out_i[(size_t)row * TOPK_N + pp] = (float)be;
                }
                if (pp > 0 && pbest - (double)best <= pbd + bd) flag = true;
                pbest = (double)best; pbd = bd;
                srow[be] = -3e38f;
            }
            if (flag) {
                unsigned idx = atomicAdd(counter, 1u);
                if (idx < lcap) list[idx] = row;
            }
        }
    }
}

// ---------------- K2 v5: fp64 partials, 16 rows x k-slice per block (r13, proven) ----------------
#define K2R 16
#define K2C 32
__global__ __launch_bounds__(256) void k2_exact(
    const float* __restrict__ x, const float* __restrict__ w,
    double* __restrict__ part2,
    const unsigned* __restrict__ counter, const int* __restrict__ list,
    unsigned lcap)
{
    __shared__ float wlds[NE][K2C + 1];
    __shared__ float xc[K2R][K2C];

    const unsigned F = min(*counter, lcap);
    const int ks = blockIdx.x & 7;
    const int rc = blockIdx.x >> 3;
    if ((unsigned)(rc * K2R) >= F) return;
    const int t = threadIdx.x;

    int rows[K2R];
#pragma unroll
    for (int i = 0; i < K2R; ++i) {
        unsigned idx = (unsigned)(rc * K2R + i);
        if (idx >= F) idx = 0;
        rows[i] = list[idx];
    }

    const int se = t >> 3;
    const int sp = (t & 7) * 4;
    const int xrr = t >> 3;
    const size_t kbase = (size_t)ks * KSLICE;

    double acc[K2R];
#pragma unroll
    for (int i = 0; i < K2R; ++i) acc[i] = 0.0;

    float4 wr[8];
#pragma unroll
    for (int it = 0; it < 8; ++it)
        wr[it] = *(const float4*)&w[(size_t)(it * 32 + se) * DIM + kbase + sp];
    float4 xr = make_float4(0.f, 0.f, 0.f, 0.f);
    if (t < 128) xr = *(const float4*)&x[(size_t)rows[xrr] * DIM + kbase + sp];

    for (int c = 0; c < KSLICE / K2C; ++c) {
        __syncthreads();
#pragma unroll
        for (int it = 0; it < 8; ++it) {
            const float* wp = (const float*)&wr[it];
#pragma unroll
            for (int q = 0; q < 4; ++q)
                wlds[it * 32 + se][sp + q] = wp[q];
        }
        if (t < 128)
            *(float4*)&xc[xrr][sp] = xr;
        {
            const int cn = (c + 1 < KSLICE / K2C) ? c + 1 : c;
            const size_t k0 = kbase + (size_t)cn * K2C;
#pragma unroll
            for (int it = 0; it < 8; ++it)
                wr[it] = *(const float4*)&w[(size_t)(it * 32 + se) * DIM + k0 + sp];
            if (t < 128) xr = *(const float4*)&x[(size_t)rows[xrr] * DIM + k0 + sp];
        }
        __syncthreads();
#pragma unroll
        for (int i = 0; i < 8; ++i) {
            float wv[4];
#pragma unroll
            for (int q = 0; q < 4; ++q) wv[q] = wlds[t][i * 4 + q];
#pragma unroll
            for (int r = 0; r < K2R; ++r) {
                const float4 xv = *(const float4*)&xc[r][i * 4];
                const float* xp = (const float*)&xv;
#pragma unroll
                for (int q = 0; q < 4; ++q)
                    acc[r] = fma((double)xp[q], (double)wv[q], acc[r]);
            }
        }
    }

#pragma unroll
    for (int r = 0; r < K2R; ++r) {
        const unsigned idx = (unsigned)(rc * K2R + r);
        if (idx < F)
            part2[((size_t)idx * 8 + ks) * NE + t] = acc[r];
    }
}

// ---------------- K2b: combine 8 fp64 slices + exact routing (register-tk) ----------------
__global__ __launch_bounds__(256) void k2b_route(
    const double* __restrict__ part2, const float* __restrict__ bias,
    float* __restrict__ out, const unsigned* __restrict__ counter,
    const int* __restrict__ list, int n, unsigned lcap)
{
    __shared__ double sc[NE];
    const unsigned F = min(*counter, lcap);
    const unsigned b = blockIdx.x;
    if (b >= F) return;
    const int t = threadIdx.x;

    double s = 0.0;
#pragma unroll
    for (int ks = 0; ks < 8; ++ks)
        s += part2[((size_t)b * 8 + ks) * NE + t];
    sc[t] = s;
    __syncthreads();

    if (t == 0) {
        const int row = list[b];
        double* srow = sc;
        double zmax = -1e300;
        for (int ee = 0; ee < NE; ++ee) zmax = fmax(zmax, srow[ee]);
        double Z = 0.0;
        for (int ee = 0; ee < NE; ++ee) {
            double p = exp(srow[ee] - zmax);
            srow[ee] = p;
            Z += p;
        }
        const double invZ = 1.0 / Z;
        double gs[NG];
#pragma unroll
        for (int g = 0; g < NG; ++g) {
            double m1 = -1e300, m2 = -1e300;
            for (int i = 0; i < GSZ; ++i) {
                double v = srow[g * GSZ + i] * invZ + (double)bias[g * GSZ + i];
                if (v > m1) { m2 = m1; m1 = v; }
                else if (v > m2) { m2 = v; }
            }
            gs[g] = m1 + m2;
        }
        unsigned keep = 0;
#pragma unroll
        for (int tt = 0; tt < TOPG; ++tt) {
            double best = -1e300; int bg = 0;
#pragma unroll
            for (int g = 0; g < NG; ++g)
                if (!((keep >> g) & 1u) && gs[g] > best) { best = gs[g]; bg = g; }
            keep |= 1u << bg;
        }
        unsigned long long tk0 = 0ull, tk1 = 0ull, tk2 = 0ull, tk3 = 0ull;
        float* out_w = out;
        float* out_i = out + (size_t)n * TOPK_N;
        for (int pp = 0; pp < TOPK_N; ++pp) {
            double best = -1e300; int be = 0;
            for (int ee = 0; ee < NE; ++ee) {
                const bool gok = (keep >> (ee >> 5)) & 1u;
                const unsigned long long m =
                    (ee < 128) ? ((ee < 64) ? tk0 : tk1) : ((ee < 192) ? tk2 : tk3);
                const bool tok = !((m >> (ee & 63)) & 1ull);
                const double ss = srow[ee] * invZ + (double)bias[ee];
                if (gok && tok && ss > best) { best = ss; be = ee; }
            }
            const unsigned long long bit = 1ull << (be & 63);
            if (be < 64)       tk0 |= bit;
            else if (be < 128) tk1 |= bit;
            else if (be < 192) tk2 |= bit;
            else               tk3 |= bit;
            out_w[(size_t)row * TOPK_N + pp] = (float)(srow[be] * invZ * 2.5);
            out_i[(size_t)row * TOPK_N + pp] = (float)be;
        }
    }
}

// ---------------- fallback (proven r6 fp64 kernel) if ws too small ----------------
#define OBM 32
#define OBK 16
#define ONCH (DIM / OBK)
__global__ __launch_bounds__(512) void gate_kernel_old(
    const float* __restrict__ x, const float* __restrict__ w,
    const float* __restrict__ bias, float* __restrict__ out, int n)
{
    __shared__ __align__(16) char smem[65536];
    float  (*w2)[OBK][NE] = reinterpret_cast<float(*)[OBK][NE]>(smem);
    double (*x2)[OBK][34] = reinterpret_cast<double(*)[OBK][34]>(smem + 32768);
    double (*sc)[OBM]     = reinterpret_cast<double(*)[OBM]>(smem);
    const int t = threadIdx.x;
    const int row0 = blockIdx.x * OBM;
    const int we = t & 255;
    const int h8 = (t >> 8) * 8;
    const size_t wbase = (size_t)we * DIM + h8;
    const int rx = t >> 2;
    const int kx = (t & 3) * 4;
    int rr = row0 + rx; if (rr > n - 1) rr = n - 1;
    const size_t xbase = (size_t)rr * DIM + kx;
    const int wv = t >> 6, lane = t & 63;
    const int h = wv & 1, rg = wv >> 1, rb = 8 * rg;
    const int e0 = 128 * h + 2 * lane;
    double acc[8][2];
#pragma unroll
    for (int i = 0; i < 8; ++i) { acc[i][0] = 0.0; acc[i][1] = 0.0; }
    float4 wra = *(const float4*)&w[wbase];
    float4 wrb = *(const float4*)&w[wbase + 4];
    float4 xr = make_float4(0.f, 0.f, 0.f, 0.f);
    if (t < 128) xr = *(const float4*)&x[xbase];
    for (int c = 0; c < ONCH; ++c) {
        const int b = c & 1;
        const float* fa = (const float*)&wra;
        const float* fb = (const float*)&wrb;
#pragma unroll
        for (int q = 0; q < 4; ++q) {
            w2[b][h8 + q][we] = fa[q];
            w2[b][h8 + 4 + q][we] = fb[q];
        }
        if (t < 128) {
            const float* fx = (const float*)&xr;
#pragma unroll
            for (int q = 0; q < 4; ++q) x2[b][kx + q][rx] = (double)fx[q];
        }
        const size_t k0 = (size_t)((c + 1 < ONCH) ? c + 1 : c) * OBK;
        wra = *(const float4*)&w[wbase + k0];
        wrb = *(const float4*)&w[wbase + k0 + 4];
        if (t < 128) xr = *(const float4*)&x[xbase + k0];
        __syncthreads();
#pragma unroll
        for (int kk = 0; kk < OBK; ++kk) {
            const float2 wf = *(const float2*)&w2[b][kk][e0];
            const double wd0 = (double)wf.x, wd1 = (double)wf.y;
            const double2 xp0 = *(const double2*)&x2[b][kk][rb];
            const double2 xp1 = *(const double2*)&x2[b][kk][rb + 2];
            const double2 xp2 = *(const double2*)&x2[b][kk][rb + 4];
            const double2 xp3 = *(const double2*)&x2[b][kk][rb + 6];
            const double xv[8] = {xp0.x, xp0.y, xp1.x, xp1.y, xp2.x, xp2.y, xp3.x, xp3.y};
#pragma unroll
            for (int i = 0; i < 8; ++i) {
                acc[i][0] = fma(xv[i], wd0, acc[i][0]);
                acc[i][1] = fma(xv[i], wd1, acc[i][1]);
            }
        }
    }
    __syncthreads();
#pragma unroll
    for (int j = 0; j < 2; ++j)
#pragma unroll
        for (int q = 0; q < 4; ++q) {
            double2 v; v.x = acc[2 * q][j]; v.y = acc[2 * q + 1][j];
            *(double2*)&sc[e0 + j][rb + 2 * q] = v;
        }
    __syncthreads();
    if (t < OBM) {
        const int row = row0 + t;
        if (row < n) {
            double zmax = -1e300;
            for (int e = 0; e < NE; ++e) zmax = fmax(zmax, sc[e][t]);
            double Z = 0.0;
            for (int e = 0; e < NE; ++e) { double p = exp(sc[e][t] - zmax); sc[e][t] = p; Z += p; }
            const double invZ = 1.0 / Z;
            double gs[NG];
            for (int g = 0; g < NG; ++g) {
                double m1 = -1e300, m2 = -1e300;
                for (int i = 0; i < GSZ; ++i) {
                    double v = sc[g * GSZ + i][t] * invZ + (double)bias[g * GSZ + i];
                    if (v > m1) { m2 = m1; m1 = v; } else if (v > m2) m2 = v;
                }
                gs[g] = m1 + m2;
            }
            unsigned keep = 0;
            for (int tt = 0; tt < TOPG; ++tt) {
                double best = -1e300; int bg = 0;
                for (int g = 0; g < NG; ++g)
                    if (!((keep >> g) & 1u) && gs[g] > best) { best = gs[g]; bg = g; }
                keep |= 1u << bg;
            }
            unsigned long long tk[4] = {0ull, 0ull, 0ull, 0ull};
            float* out_w = out;
            float* out_i = out + (size_t)n * TOPK_N;
            for (int pp = 0; pp < TOPK_N; ++pp) {
                double best = -1e300; int be = 0;
                for (int e = 0; e < NE; ++e) {
                    if (!((keep >> (e >> 5)) & 1u)) continue;
                    if ((tk[e >> 6] >> (e & 63)) & 1ull) continue;
                    double s = sc[e][t] * invZ + (double)bias[e];
                    if (s > best) { best = s; be = e; }
                }
                tk[be >> 6] |= 1ull << (be & 63);
                out_w[(size_t)row * TOPK_N + pp] = (float)(sc[be][t] * invZ * 2.5);
                out_i[(size_t)row * TOPK_N + pp] = (float)be;
            }
        }
    }
}

extern "C" void kernel_launch(void* const* d_in, const int* in_sizes, int n_in,
                              void* d_out, int out_size, void* d_ws, size_t ws_size,
                              hipStream_t stream) {
    const float* x  = (const float*)d_in[0];
    const float* w  = (const float*)d_in[1];
    const float* b  = (const float*)d_in[2];
    float* out      = (float*)d_out;
    const int n     = in_sizes[0] / DIM;
    const int np    = (n + BM - 1) & ~(BM - 1);
    const int nrb   = np / BM;

    const size_t WBYTES   = (size_t)16 * NKT * 64 * 8 * 2;
    const size_t off_list = 4096;
    const size_t off_wh   = off_list + (((size_t)np * 4 + 255) & ~(size_t)255);
    const size_t off_wl   = off_wh + WBYTES;
    const size_t off_part = off_wl + WBYTES;
    const size_t part_sz  = (size_t)KSPLIT * np * NE * 4;
    const size_t p2_sz    = (size_t)FCAP * 8 * NE * 8;
    const size_t off_z    = off_part + (part_sz > p2_sz ? part_sz : p2_sz);
    const size_t z_sz     = (size_t)np * NE * 4;
    const size_t need     = off_z + z_sz;

    if (ws_size < need) {
        gate_kernel_old<<<(n + OBM - 1) / OBM, 512, 0, stream>>>(x, w, b, out, n);
        return;
    }
    char* ws = (char*)d_ws;
    unsigned* flagctr   = (unsigned*)ws;
    int* list           = (int*)(ws + off_list);
    unsigned short* wh  = (unsigned short*)(ws + off_wh);
    unsigned short* wl  = (unsigned short*)(ws + off_wl);
    float* part         = (float*)(ws + off_part);
    double* part2       = (double*)(ws + off_part);
    float* zbuf         = (float*)(ws + off_z);

    const unsigned lcap = (unsigned)((np < FCAP) ? np : FCAP);

    hipMemsetAsync(ws, 0, 64, stream);
    k0_repack<<<(16 * NKT * 64) / 256, 256, 0, stream>>>(w, wh, wl);
    k1_gemm<<<nrb * KSPLIT, 512, 0, stream>>>(x, wh, wl, part, n, np);
    k1b_sum<<<np / RSB, 256, 0, stream>>>(part, zbuf, np);
    k1b_tail<<<np / 32, 256, 0, stream>>>(zbuf, b, out, flagctr, list, n, lcap);
    k2_exact<<<((lcap + K2R - 1) / K2R) * 8, 256, 0, stream>>>(x, w, part2, flagctr, list, lcap);
    k2b_route<<<lcap, 256, 0, stream>>>(part2, b, out, flagctr, list, n, lcap);
}

// Round 20
// 458.877 us; speedup vs baseline: 1.3921x; 1.3209x over previous
//
#include <hip/hip_runtime.h>
#include <math.h>

#define DIM 7168
#define NE 256
#define NG 8
#define GSZ 32
#define TOPG 4
#define TOPK_N 8
#define NKT 224          // DIM/32 k-tiles total
#define KSPLIT 8
#define KTS 28           // NKT/KSPLIT
#define KSLICE 896       // DIM/KSPLIT
#define BM 128

typedef short bf16x8 __attribute__((ext_vector_type(8)));
typedef float f32x4 __attribute__((ext_vector_type(4)));

#define DREL 4e-5
#define EABS 1e-7
#define FCAP 4096

__device__ __forceinline__ unsigned short bf16_rne(float f) {
    unsigned u = __float_as_uint(f);
    unsigned r = u + 0x7FFFu + ((u >> 16) & 1u);
    return (unsigned short)(r >> 16);
}
__device__ __forceinline__ float bf16_to_f32(unsigned short h) {
    return __uint_as_float(((unsigned)h) << 16);
}

// ---------------- K0: repack W into fragment-major bf16 hi/lo ----------------
__global__ void k0_repack(const float* __restrict__ w,
                          unsigned short* __restrict__ wh,
                          unsigned short* __restrict__ wl) {
    const int gid = blockIdx.x * 256 + threadIdx.x;
    if (gid >= 16 * NKT * 64) return;
    const int l  = gid & 63;
    const int kt = (gid >> 6) % NKT;
    const int ct = gid / (NKT * 64);
    const int e  = ct * 16 + (l & 15);
    const int k0 = kt * 32 + (l >> 4) * 8;
    const float* src = w + (size_t)e * DIM + k0;
    float4 u0 = *(const float4*)src;
    float4 u1 = *(const float4*)(src + 4);
    const float uu[8] = {u0.x, u0.y, u0.z, u0.w, u1.x, u1.y, u1.z, u1.w};
    ushort4 ho[2], lo[2];
    unsigned short* hp = (unsigned short*)ho;
    unsigned short* lp = (unsigned short*)lo;
#pragma unroll
    for (int q = 0; q < 8; ++q) {
        unsigned short hb = bf16_rne(uu[q]);
        float hf = bf16_to_f32(hb);
        unsigned short lb = bf16_rne(uu[q] - hf);
        hp[q] = hb; lp[q] = lb;
    }
    *(ushort4*)(wh + (size_t)gid * 8)     = ho[0];
    *(ushort4*)(wh + (size_t)gid * 8 + 4) = ho[1];
    *(ushort4*)(wl + (size_t)gid * 8)     = lo[0];
    *(ushort4*)(wl + (size_t)gid * 8 + 4) = lo[1];
}

// ---------------- K1: fragment-direct split-bf16 GEMM, BM=128, SW-pipelined (r19) ----------------
__global__ __launch_bounds__(512, 2) void k1_gemm(
    const float* __restrict__ x,
    const unsigned short* __restrict__ wh, const unsigned short* __restrict__ wl,
    float* __restrict__ part, int n, int np)
{
    const int t  = threadIdx.x;
    const int l  = t & 63;
    const int wv = t >> 6;
    const int ks = blockIdx.x & 7;
    const int rb = blockIdx.x >> 3;
    const int rtb = 2 * (wv & 3);
    const int ctb = 8 * (wv >> 2);
    const int mrow  = l & 15;
    const int kslot = l >> 4;

    f32x4 acc[2][8];
#pragma unroll
    for (int rr = 0; rr < 2; ++rr)
#pragma unroll
        for (int ci = 0; ci < 8; ++ci) acc[rr][ci] = (f32x4){0.f, 0.f, 0.f, 0.f};

    size_t xoff[2];
#pragma unroll
    for (int rr = 0; rr < 2; ++rr) {
        int row = rb * BM + (rtb + rr) * 16 + mrow;
        if (row > n - 1) row = n - 1;
        xoff[rr] = (size_t)row * DIM + (size_t)ks * KSLICE + kslot * 8;
    }
    const size_t bbase = (size_t)l * 8;

    auto loadB = [&](int ttl, int half, bf16x8* dh, bf16x8* dl) {
#pragma unroll
        for (int ci = 0; ci < 4; ++ci) {
            const int ct = ctb + half * 4 + ci;
            const size_t fb = ((size_t)(ct * NKT + ks * KTS + ttl) * 64) * 8 + bbase;
            dh[ci] = *(const bf16x8*)(wh + fb);
            dl[ci] = *(const bf16x8*)(wl + fb);
        }
    };
    auto splitx = [&](float4 u0, float4 u1, bf16x8& hh, bf16x8& ll) {
        const float uu[8] = {u0.x, u0.y, u0.z, u0.w, u1.x, u1.y, u1.z, u1.w};
        bf16x8 h, lo;
#pragma unroll
        for (int q = 0; q < 8; ++q) {
            const unsigned u  = __float_as_uint(uu[q]);
            const unsigned hr = (u + 0x7FFFu + ((u >> 16) & 1u)) & 0xFFFF0000u;
            const float lofv  = uu[q] - __uint_as_float(hr);
            h[q]  = (short)(hr >> 16);
            lo[q] = (short)(__float_as_uint(lofv) >> 16);
        }
        hh = h; ll = lo;
    };

    bf16x8 bhb[2][4], blb[2][4];
    float4 px0a, px0b, px1a, px1b;

    px0a = *(const float4*)(x + xoff[0]);
    px0b = *(const float4*)(x + xoff[0] + 4);
    px1a = *(const float4*)(x + xoff[1]);
    px1b = *(const float4*)(x + xoff[1] + 4);
    loadB(0, 0, bhb[0], blb[0]);

#pragma unroll 1
    for (int tt = 0; tt < KTS; ++tt) {
        const int tn = (tt + 1 < KTS) ? tt + 1 : tt;
        bf16x8 ah0, al0, ah1, al1;
        splitx(px0a, px0b, ah0, al0);
        splitx(px1a, px1b, ah1, al1);
        px0a = *(const float4*)(x + xoff[0] + (size_t)tn * 32);
        px0b = *(const float4*)(x + xoff[0] + (size_t)tn * 32 + 4);
        px1a = *(const float4*)(x + xoff[1] + (size_t)tn * 32);
        px1b = *(const float4*)(x + xoff[1] + (size_t)tn * 32 + 4);
        loadB(tt, 1, bhb[1], blb[1]);
#pragma unroll
        for (int ci = 0; ci < 4; ++ci) {
            acc[0][ci] = __builtin_amdgcn_mfma_f32_16x16x32_bf16(ah0, bhb[0][ci], acc[0][ci], 0, 0, 0);
            acc[0][ci] = __builtin_amdgcn_mfma_f32_16x16x32_bf16(ah0, blb[0][ci], acc[0][ci], 0, 0, 0);
            acc[0][ci] = __builtin_amdgcn_mfma_f32_16x16x32_bf16(al0, bhb[0][ci], acc[0][ci], 0, 0, 0);
            acc[1][ci] = __builtin_amdgcn_mfma_f32_16x16x32_bf16(ah1, bhb[0][ci], acc[1][ci], 0, 0, 0);
            acc[1][ci] = __builtin_amdgcn_mfma_f32_16x16x32_bf16(ah1, blb[0][ci], acc[1][ci], 0, 0, 0);
            acc[1][ci] = __builtin_amdgcn_mfma_f32_16x16x32_bf16(al1, bhb[0][ci], acc[1][ci], 0, 0, 0);
        }
        loadB(tn, 0, bhb[0], blb[0]);
#pragma unroll
        for (int ci = 0; ci < 4; ++ci) {
            acc[0][4 + ci] = __builtin_amdgcn_mfma_f32_16x16x32_bf16(ah0, bhb[1][ci], acc[0][4 + ci], 0, 0, 0);
            acc[0][4 + ci] = __builtin_amdgcn_mfma_f32_16x16x32_bf16(ah0, blb[1][ci], acc[0][4 + ci], 0, 0, 0);
            acc[0][4 + ci] = __builtin_amdgcn_mfma_f32_16x16x32_bf16(al0, bhb[1][ci], acc[0][4 + ci], 0, 0, 0);
            acc[1][4 + ci] = __builtin_amdgcn_mfma_f32_16x16x32_bf16(ah1, bhb[1][ci], acc[1][4 + ci], 0, 0, 0);
            acc[1][4 + ci] = __builtin_amdgcn_mfma_f32_16x16x32_bf16(ah1, blb[1][ci], acc[1][4 + ci], 0, 0, 0);
            acc[1][4 + ci] = __builtin_amdgcn_mfma_f32_16x16x32_bf16(al1, blb[1][ci] * 0 + bhb[1][ci], acc[1][4 + ci], 0, 0, 0);
        }
    }

    float* pb = part + (size_t)ks * np * NE;
#pragma unroll
    for (int rr = 0; rr < 2; ++rr)
#pragma unroll
        for (int ci = 0; ci < 8; ++ci) {
            const int rl = rb * BM + (rtb + rr) * 16 + 4 * kslot;
            const int e  = (ctb + ci) * 16 + mrow;
#pragma unroll
            for (int j = 0; j < 4; ++j)
                pb[(size_t)(rl + j) * NE + e] = acc[rr][ci][j];
        }
}

// ---------------- K1b-sum: TLP streaming combine -> zbuf ----------------
#define RSB 4
__global__ __launch_bounds__(256) void k1b_sum(
    const float* __restrict__ part, float* __restrict__ zbuf, int np)
{
    const int t  = threadIdx.x;
    const int r0 = blockIdx.x * RSB;
#pragma unroll
    for (int r = 0; r < RSB; ++r) {
        const size_t off = (size_t)(r0 + r) * NE + t;
        float z = 0.f;
#pragma unroll
        for (int ks = 0; ks < KSPLIT; ++ks)
            z += part[(size_t)ks * np * NE + off];
        zbuf[off] = z;
    }
}

// ---------------- K1b-tail v4: precompute-s + destructive f32 argmax ----------------
#define SCW 260
__global__ __launch_bounds__(256) void k1b_tail(
    const float* __restrict__ zbuf, const float* __restrict__ bias,
    float* __restrict__ out, unsigned* __restrict__ counter,
    int* __restrict__ list, int n, unsigned lcap)
{
    __shared__ __align__(16) float sc[32][SCW];
    __shared__ float sbias[NE];
    const int t  = threadIdx.x;
    const int r0 = blockIdx.x * 32;
    sbias[t] = bias[t];
#pragma unroll
    for (int r = 0; r < 32; ++r)
        sc[r][t] = zbuf[(size_t)(r0 + r) * NE + t];
    __syncthreads();

    if (t < 32) {
        const int row = r0 + t;
        if (row < n) {
            float* srow = sc[t];
            float zmaxf = -3e38f;
            for (int e = 0; e < NE; ++e) zmaxf = fmaxf(zmaxf, srow[e]);
            double Z = 0.0;
            for (int e = 0; e < NE; ++e) {
                float p = __expf(srow[e] - zmaxf);
                srow[e] = p;
                Z += (double)p;
            }
            const double invZ = 1.0 / Z;

            bool flag = false;
            double gs[NG], dg[NG];
#pragma unroll
            for (int g = 0; g < NG; ++g) {
                double v1 = -1e300, v2 = -1e300, v3 = -1e300;
                double d1 = 0, d2 = 0, d3 = 0;
                for (int i = 0; i < GSZ; ++i) {
                    const int e = g * GSZ + i;
                    double p = (double)srow[e] * invZ;
                    double v = p + (double)sbias[e];
                    double d = DREL * p;
                    srow[e] = (float)v;
                    if (v > v1)      { v3 = v2; d3 = d2; v2 = v1; d2 = d1; v1 = v; d1 = d; }
                    else if (v > v2) { v3 = v2; d3 = d2; v2 = v;  d2 = d; }
                    else if (v > v3) { v3 = v;  d3 = d; }
                }
                if (v2 - v3 <= d2 + d3) flag = true;
                gs[g] = v1 + v2; dg[g] = d1 + d2;
            }
            unsigned keep = 0;
#pragma unroll
            for (int tt = 0; tt < TOPG; ++tt) {
                double best = -1e300; int bg = 0;
#pragma unroll
                for (int g = 0; g < NG; ++g)
                    if (!((keep >> g) & 1u) && gs[g] > best) { best = gs[g]; bg = g; }
                keep |= 1u << bg;
            }
            {
                double mn = 1e300, mx = -1e300;
#pragma unroll
                for (int g = 0; g < NG; ++g) {
                    if ((keep >> g) & 1u) mn = fmin(mn, gs[g] - dg[g]);
                    else                  mx = fmax(mx, gs[g] + dg[g]);
                }
                if (mn <= mx) flag = true;
            }
#pragma unroll
            for (int g = 0; g < NG; ++g) {
                if (!((keep >> g) & 1u)) {
#pragma unroll
                    for (int i = 0; i < GSZ; i += 4)
                        *(float4*)&srow[g * GSZ + i] =
                            make_float4(-3e38f, -3e38f, -3e38f, -3e38f);
                }
            }
            double pbest = 0.0, pbd = 0.0;
            float* out_w = out;
            float* out_i = out + (size_t)n * TOPK_N;
            for (int pp = 0; pp < 9; ++pp) {
                float best = -3e38f; int be = 0;
                for (int i = 0; i < NE / 4; ++i) {
                    const float4 v = *(const float4*)&srow[4 * i];
                    float m01 = (v.x >= v.y) ? v.x : v.y;
                    int   i01 = (v.x >= v.y) ? 0 : 1;
                    float m23 = (v.z >= v.w) ? v.z : v.w;
                    int   i23 = (v.z >= v.w) ? 2 : 3;
                    float m   = (m01 >= m23) ? m01 : m23;
                    int   iq  = (m01 >= m23) ? i01 : i23;
                    if (m > best) { best = m; be = 4 * i + iq; }
                }
                const double pt = fmax((double)best - (double)sbias[be], 0.0);
                const double bd = DREL * pt + EABS;
                if (pp < TOPK_N) {
                    out_w[(size_t)row * TOPK_N + pp] = (float)(pt * 2.5);
                    out_i[(size_t)row * TOPK_N + pp] = (float)be;
                }
                if (pp > 0 && pbest - (double)best <= pbd + bd) flag = true;
                pbest = (double)best; pbd = bd;
                srow[be] = -3e38f;
            }
            if (flag) {
                unsigned idx = atomicAdd(counter, 1u);
                if (idx < lcap) list[idx] = row;
            }
        }
    }
}

// ---------------- K2 v6: fp64 partials, 4 rows x k-slice per block ----------------
#define K2R 4
#define K2C 32
__global__ __launch_bounds__(256) void k2_exact(
    const float* __restrict__ x, const float* __restrict__ w,
    double* __restrict__ part2,
    const unsigned* __restrict__ counter, const int* __restrict__ list,
    unsigned lcap)
{
    __shared__ float wlds[NE][K2C + 1];   // 33,792 B; stride 33 -> conflict-free b32
    __shared__ float xc[K2R][K2C];        // 512 B

    const unsigned F = min(*counter, lcap);
    const int ks = blockIdx.x & 7;
    const int rc = blockIdx.x >> 3;
    if ((unsigned)(rc * K2R) >= F) return;
    const int t = threadIdx.x;

    int rows[K2R];
#pragma unroll
    for (int i = 0; i < K2R; ++i) {
        unsigned idx = (unsigned)(rc * K2R + i);
        if (idx >= F) idx = 0;
        rows[i] = list[idx];
    }

    const int se = t >> 3;             // expert offset within 32-group
    const int sp = (t & 7) * 4;        // k quad within chunk
    const int xrr = t >> 3;            // x staging row (t<32 -> 0..3)
    const size_t kbase = (size_t)ks * KSLICE;

    double acc[K2R];
#pragma unroll
    for (int i = 0; i < K2R; ++i) acc[i] = 0.0;

    float4 wr[8];
#pragma unroll
    for (int it = 0; it < 8; ++it)
        wr[it] = *(const float4*)&w[(size_t)(it * 32 + se) * DIM + kbase + sp];
    float4 xr = make_float4(0.f, 0.f, 0.f, 0.f);
    if (t < 32) xr = *(const float4*)&x[(size_t)rows[xrr] * DIM + kbase + sp];

    for (int c = 0; c < KSLICE / K2C; ++c) {   // 28 chunks
        __syncthreads();
#pragma unroll
        for (int it = 0; it < 8; ++it) {
            const float* wp = (const float*)&wr[it];
#pragma unroll
            for (int q = 0; q < 4; ++q)
                wlds[it * 32 + se][sp + q] = wp[q];
        }
        if (t < 32)
            *(float4*)&xc[xrr][sp] = xr;
        {
            const int cn = (c + 1 < KSLICE / K2C) ? c + 1 : c;
            const size_t k0 = kbase + (size_t)cn * K2C;
#pragma unroll
            for (int it = 0; it < 8; ++it)
                wr[it] = *(const float4*)&w[(size_t)(it * 32 + se) * DIM + k0 + sp];
            if (t < 32) xr = *(const float4*)&x[(size_t)rows[xrr] * DIM + k0 + sp];
        }
        __syncthreads();
        // compute: thread t = expert t; 4 sequential fp64 chains, k ascending
#pragma unroll
        for (int i = 0; i < 8; ++i) {
            float wv[4];
#pragma unroll
            for (int q = 0; q < 4; ++q) wv[q] = wlds[t][i * 4 + q];
#pragma unroll
            for (int r = 0; r < K2R; ++r) {
                const float4 xv = *(const float4*)&xc[r][i * 4];
                const float* xp = (const float*)&xv;
#pragma unroll
                for (int q = 0; q < 4; ++q)
                    acc[r] = fma((double)xp[q], (double)wv[q], acc[r]);
            }
        }
    }

#pragma unroll
    for (int r = 0; r < K2R; ++r) {
        const unsigned idx = (unsigned)(rc * K2R + r);
        if (idx < F)
            part2[((size_t)idx * 8 + ks) * NE + t] = acc[r];
    }
}

// ---------------- K2b: combine 8 fp64 slices + exact routing (register-tk) ----------------
__global__ __launch_bounds__(256) void k2b_route(
    const double* __restrict__ part2, const float* __restrict__ bias,
    float* __restrict__ out, const unsigned* __restrict__ counter,
    const int* __restrict__ list, int n, unsigned lcap)
{
    __shared__ double sc[NE];
    const unsigned F = min(*counter, lcap);
    const unsigned b = blockIdx.x;
    if (b >= F) return;
    const int t = threadIdx.x;

    double s = 0.0;
#pragma unroll
    for (int ks = 0; ks < 8; ++ks)
        s += part2[((size_t)b * 8 + ks) * NE + t];
    sc[t] = s;
    __syncthreads();

    if (t == 0) {
        const int row = list[b];
        double* srow = sc;
        double zmax = -1e300;
        for (int ee = 0; ee < NE; ++ee) zmax = fmax(zmax, srow[ee]);
        double Z = 0.0;
        for (int ee = 0; ee < NE; ++ee) {
            double p = exp(srow[ee] - zmax);
            srow[ee] = p;
            Z += p;
        }
        const double invZ = 1.0 / Z;
        double gs[NG];
#pragma unroll
        for (int g = 0; g < NG; ++g) {
            double m1 = -1e300, m2 = -1e300;
            for (int i = 0; i < GSZ; ++i) {
                double v = srow[g * GSZ + i] * invZ + (double)bias[g * GSZ + i];
                if (v > m1) { m2 = m1; m1 = v; }
                else if (v > m2) { m2 = v; }
            }
            gs[g] = m1 + m2;
        }
        unsigned keep = 0;
#pragma unroll
        for (int tt = 0; tt < TOPG; ++tt) {
            double best = -1e300; int bg = 0;
#pragma unroll
            for (int g = 0; g < NG; ++g)
                if (!((keep >> g) & 1u) && gs[g] > best) { best = gs[g]; bg = g; }
            keep |= 1u << bg;
        }
        unsigned long long tk0 = 0ull, tk1 = 0ull, tk2 = 0ull, tk3 = 0ull;
        float* out_w = out;
        float* out_i = out + (size_t)n * TOPK_N;
        for (int pp = 0; pp < TOPK_N; ++pp) {
            double best = -1e300; int be = 0;
            for (int ee = 0; ee < NE; ++ee) {
                const bool gok = (keep >> (ee >> 5)) & 1u;
                const unsigned long long m =
                    (ee < 128) ? ((ee < 64) ? tk0 : tk1) : ((ee < 192) ? tk2 : tk3);
                const bool tok = !((m >> (ee & 63)) & 1ull);
                const double ss = srow[ee] * invZ + (double)bias[ee];
                if (gok && tok && ss > best) { best = ss; be = ee; }
            }
            const unsigned long long bit = 1ull << (be & 63);
            if (be < 64)       tk0 |= bit;
            else if (be < 128) tk1 |= bit;
            else if (be < 192) tk2 |= bit;
            else               tk3 |= bit;
            out_w[(size_t)row * TOPK_N + pp] = (float)(srow[be] * invZ * 2.5);
            out_i[(size_t)row * TOPK_N + pp] = (float)be;
        }
    }
}

// ---------------- fallback (proven r6 fp64 kernel) if ws too small ----------------
#define OBM 32
#define OBK 16
#define ONCH (DIM / OBK)
__global__ __launch_bounds__(512) void gate_kernel_old(
    const float* __restrict__ x, const float* __restrict__ w,
    const float* __restrict__ bias, float* __restrict__ out, int n)
{
    __shared__ __align__(16) char smem[65536];
    float  (*w2)[OBK][NE] = reinterpret_cast<float(*)[OBK][NE]>(smem);
    double (*x2)[OBK][34] = reinterpret_cast<double(*)[OBK][34]>(smem + 32768);
    double (*sc)[OBM]     = reinterpret_cast<double(*)[OBM]>(smem);
    const int t = threadIdx.x;
    const int row0 = blockIdx.x * OBM;
    const int we = t & 255;
    const int h8 = (t >> 8) * 8;
    const size_t wbase = (size_t)we * DIM + h8;
    const int rx = t >> 2;
    const int kx = (t & 3) * 4;
    int rr = row0 + rx; if (rr > n - 1) rr = n - 1;
    const size_t xbase = (size_t)rr * DIM + kx;
    const int wv = t >> 6, lane = t & 63;
    const int h = wv & 1, rg = wv >> 1, rb = 8 * rg;
    const int e0 = 128 * h + 2 * lane;
    double acc[8][2];
#pragma unroll
    for (int i = 0; i < 8; ++i) { acc[i][0] = 0.0; acc[i][1] = 0.0; }
    float4 wra = *(const float4*)&w[wbase];
    float4 wrb = *(const float4*)&w[wbase + 4];
    float4 xr = make_float4(0.f, 0.f, 0.f, 0.f);
    if (t < 128) xr = *(const float4*)&x[xbase];
    for (int c = 0; c < ONCH; ++c) {
        const int b = c & 1;
        const float* fa = (const float*)&wra;
        const float* fb = (const float*)&wrb;
#pragma unroll
        for (int q = 0; q < 4; ++q) {
            w2[b][h8 + q][we] = fa[q];
            w2[b][h8 + 4 + q][we] = fb[q];
        }
        if (t < 128) {
            const float* fx = (const float*)&xr;
#pragma unroll
            for (int q = 0; q < 4; ++q) x2[b][kx + q][rx] = (double)fx[q];
        }
        const size_t k0 = (size_t)((c + 1 < ONCH) ? c + 1 : c) * OBK;
        wra = *(const float4*)&w[wbase + k0];
        wrb = *(const float4*)&w[wbase + k0 + 4];
        if (t < 128) xr = *(const float4*)&x[xbase + k0];
        __syncthreads();
#pragma unroll
        for (int kk = 0; kk < OBK; ++kk) {
            const float2 wf = *(const float2*)&w2[b][kk][e0];
            const double wd0 = (double)wf.x, wd1 = (double)wf.y;
            const double2 xp0 = *(const double2*)&x2[b][kk][rb];
            const double2 xp1 = *(const double2*)&x2[b][kk][rb + 2];
            const double2 xp2 = *(const double2*)&x2[b][kk][rb + 4];
            const double2 xp3 = *(const double2*)&x2[b][kk][rb + 6];
            const double xv[8] = {xp0.x, xp0.y, xp1.x, xp1.y, xp2.x, xp2.y, xp3.x, xp3.y};
#pragma unroll
            for (int i = 0; i < 8; ++i) {
                acc[i][0] = fma(xv[i], wd0, acc[i][0]);
                acc[i][1] = fma(xv[i], wd1, acc[i][1]);
            }
        }
    }
    __syncthreads();
#pragma unroll
    for (int j = 0; j < 2; ++j)
#pragma unroll
        for (int q = 0; q < 4; ++q) {
            double2 v; v.x = acc[2 * q][j]; v.y = acc[2 * q + 1][j];
            *(double2*)&sc[e0 + j][rb + 2 * q] = v;
        }
    __syncthreads();
    if (t < OBM) {
        const int row = row0 + t;
        if (row < n) {
            double zmax = -1e300;
            for (int e = 0; e < NE; ++e) zmax = fmax(zmax, sc[e][t]);
            double Z = 0.0;
            for (int e = 0; e < NE; ++e) { double p = exp(sc[e][t] - zmax); sc[e][t] = p; Z += p; }
            const double invZ = 1.0 / Z;
            double gs[NG];
            for (int g = 0; g < NG; ++g) {
                double m1 = -1e300, m2 = -1e300;
                for (int i = 0; i < GSZ; ++i) {
                    double v = sc[g * GSZ + i][t] * invZ + (double)bias[g * GSZ + i];
                    if (v > m1) { m2 = m1; m1 = v; } else if (v > m2) m2 = v;
                }
                gs[g] = m1 + m2;
            }
            unsigned keep = 0;
            for (int tt = 0; tt < TOPG; ++tt) {
                double best = -1e300; int bg = 0;
                for (int g = 0; g < NG; ++g)
                    if (!((keep >> g) & 1u) && gs[g] > best) { best = gs[g]; bg = g; }
                keep |= 1u << bg;
            }
            unsigned long long tk[4] = {0ull, 0ull, 0ull, 0ull};
            float* out_w = out;
            float* out_i = out + (size_t)n * TOPK_N;
            for (int pp = 0; pp < TOPK_N; ++pp) {
                double best = -1e300; int be = 0;
                for (int e = 0; e < NE; ++e) {
                    if (!((keep >> (e >> 5)) & 1u)) continue;
                    if ((tk[e >> 6] >> (e & 63)) & 1ull) continue;
                    double s = sc[e][t] * invZ + (double)bias[e];
                    if (s > best) { best = s; be = e; }
                }
                tk[be >> 6] |= 1ull << (be & 63);
                out_w[(size_t)row * TOPK_N + pp] = (float)(sc[be][t] * invZ * 2.5);
                out_i[(size_t)row * TOPK_N + pp] = (float)be;
            }
        }
    }
}

extern "C" void kernel_launch(void* const* d_in, const int* in_sizes, int n_in,
                              void* d_out, int out_size, void* d_ws, size_t ws_size,
                              hipStream_t stream) {
    const float* x  = (const float*)d_in[0];
    const float* w  = (const float*)d_in[1];
    const float* b  = (const float*)d_in[2];
    float* out      = (float*)d_out;
    const int n     = in_sizes[0] / DIM;
    const int np    = (n + BM - 1) & ~(BM - 1);
    const int nrb   = np / BM;

    const size_t WBYTES   = (size_t)16 * NKT * 64 * 8 * 2;
    const size_t off_list = 4096;
    const size_t off_wh   = off_list + (((size_t)np * 4 + 255) & ~(size_t)255);
    const size_t off_wl   = off_wh + WBYTES;
    const size_t off_part = off_wl + WBYTES;
    const size_t part_sz  = (size_t)KSPLIT * np * NE * 4;
    const size_t p2_sz    = (size_t)FCAP * 8 * NE * 8;
    const size_t off_z    = off_part + (part_sz > p2_sz ? part_sz : p2_sz);
    const size_t z_sz     = (size_t)np * NE * 4;
    const size_t need     = off_z + z_sz;

    if (ws_size < need) {
        gate_kernel_old<<<(n + OBM - 1) / OBM, 512, 0, stream>>>(x, w, b, out, n);
        return;
    }
    char* ws = (char*)d_ws;
    unsigned* flagctr   = (unsigned*)ws;
    int* list           = (int*)(ws + off_list);
    unsigned short* wh  = (unsigned short*)(ws + off_wh);
    unsigned short* wl  = (unsigned short*)(ws + off_wl);
    float* part         = (float*)(ws + off_part);
    double* part2       = (double*)(ws + off_part);
    float* zbuf         = (float*)(ws + off_z);

    const unsigned lcap = (unsigned)((np < FCAP) ? np : FCAP);

    hipMemsetAsync(ws, 0, 64, stream);
    k0_repack<<<(16 * NKT * 64) / 256, 256, 0, stream>>>(w, wh, wl);
    k1_gemm<<<nrb * KSPLIT, 512, 0, stream>>>(x, wh, wl, part, n, np);
    k1b_sum<<<np / RSB, 256, 0, stream>>>(part, zbuf, np);
    k1b_tail<<<np / 32, 256, 0, stream>>>(zbuf, b, out, flagctr, list, n, lcap);
    k2_exact<<<((lcap + K2R - 1) / K2R) * 8, 256, 0, stream>>>(x, w, part2, flagctr, list, lcap);
    k2b_route<<<lcap, 256, 0, stream>>>(part2, b, out, flagctr, list, n, lcap);
}